// Round 1
// baseline (82.856 us; speedup 1.0000x reference)
//
#include <hip/hip_runtime.h>
#include <math.h>

// FreqEmbedding: seq [16,512,64] f32 -> out [16,512,65,64] f32
// reflect-pad(64) -> hanning(128) frames -> rfft(128) -> complex standardize
// over (L,F) per (B,C) -> abs.

#define B_ 16
#define L_ 512
#define C_ 64
#define W_ 128
#define F_ 65
#define NLF (L_ * F_)  // 33280

// ---------- compile-time trig tables (fold to VALU literals) ----------
constexpr double kPI = 3.14159265358979323846;

constexpr double csin_(double x) {
  while (x > kPI) x -= 2.0 * kPI;
  while (x < -kPI) x += 2.0 * kPI;
  double t = x, s = x, x2 = x * x;
  for (int i = 1; i <= 24; ++i) {
    t *= -x2 / ((2.0 * i) * (2.0 * i + 1.0));
    s += t;
  }
  return s;
}
constexpr double ccos_(double x) { return csin_(kPI / 2.0 - x); }

constexpr int bitrev6(int n) {
  int r = 0;
  for (int i = 0; i < 6; ++i) r |= ((n >> i) & 1) << (5 - i);
  return r;
}

struct Tables {
  float win[128];        // hanning
  float twr[32], twi[32]; // exp(-2*pi*i*j/64)
  float cur[32], cui[32]; // exp(-2*pi*i*k/128), k=0..31
  constexpr Tables() : win(), twr(), twi(), cur(), cui() {
    for (int n = 0; n < 128; ++n)
      win[n] = (float)(0.5 - 0.5 * ccos_(2.0 * kPI * n / 127.0));
    for (int j = 0; j < 32; ++j) {
      twr[j] = (float)ccos_(2.0 * kPI * j / 64.0);
      twi[j] = (float)(-csin_(2.0 * kPI * j / 64.0));
    }
    for (int k = 0; k < 32; ++k) {
      cur[k] = (float)ccos_(2.0 * kPI * k / 128.0);
      cui[k] = (float)(-csin_(2.0 * kPI * k / 128.0));
    }
  }
};
constexpr Tables TBL{};

// reflect index into [0, 512)
__device__ __forceinline__ int refl(int t) {
  t = t < 0 ? -t : t;
  return t >= L_ ? (2 * (L_ - 1) - t) : t;
}

// Computes 2*rfft(win * frame) bins and feeds them to `consume(f, re, im)`.
// The uniform factor 2 cancels in the standardization.
template <typename F>
__device__ __forceinline__ void fft_bins(const float* __restrict__ seq,
                                         int b, int l, int c, F&& consume) {
  float zr[64], zi[64];
  const float* base = seq + ((size_t)b * L_) * C_ + c;

  // load in bit-reversed order, pack even/odd, apply window
#pragma unroll
  for (int n = 0; n < 64; ++n) {
    const int m = bitrev6(n);
    const int w0 = 2 * m, w1 = 2 * m + 1;
    const int t0 = refl(l + w0 - 64);
    const int t1 = refl(l + w1 - 64);
    zr[n] = base[(size_t)t0 * C_] * TBL.win[w0];
    zi[n] = base[(size_t)t1 * C_] * TBL.win[w1];
  }

  // 64-point complex DIT FFT, fully unrolled, twiddles are literals
#pragma unroll
  for (int s = 0; s < 6; ++s) {
    const int half = 1 << s;
    const int len = half << 1;
#pragma unroll
    for (int j = 0; j < half; ++j) {
      const float wr = TBL.twr[j << (5 - s)];
      const float wi = TBL.twi[j << (5 - s)];
#pragma unroll
      for (int base2 = 0; base2 < 64; base2 += len) {
        const int a = base2 + j;
        const int b2 = a + half;
        const float tr = wr * zr[b2] - wi * zi[b2];
        const float ti = wr * zi[b2] + wi * zr[b2];
        zr[b2] = zr[a] - tr;
        zi[b2] = zi[a] - ti;
        zr[a] += tr;
        zi[a] += ti;
      }
    }
  }

  // unpack real-FFT bins (scaled by 2)
  consume(0, 2.0f * (zr[0] + zi[0]), 0.0f);
  consume(64, 2.0f * (zr[0] - zi[0]), 0.0f);
  consume(32, 2.0f * zr[32], -2.0f * zi[32]);
#pragma unroll
  for (int k = 1; k < 32; ++k) {
    const float cr = TBL.cur[k], ci = TBL.cui[k];
    const float Er = zr[k] + zr[64 - k];
    const float Ei = zi[k] - zi[64 - k];
    const float Or = zi[k] + zi[64 - k];
    const float Oi = zr[64 - k] - zr[k];
    const float wOr = cr * Or - ci * Oi;
    const float wOi = cr * Oi + ci * Or;
    consume(k, Er + wOr, Ei + wOi);
    consume(64 - k, Er - wOr, wOi - Ei);
  }
}

// ws layout (floats): [0..1023] sum_re, [1024..2047] sum_im, [2048..3071] sum_sq,
//                     [3072..4095] mu_re, [4096..5119] mu_im, [5120..6143] inv_std
__global__ void __launch_bounds__(256, 2)
fe_reduce_kernel(const float* __restrict__ seq, float* __restrict__ acc) {
  const int p = blockIdx.x * 4 + (threadIdx.x >> 6);
  const int b = __builtin_amdgcn_readfirstlane(p >> 9);
  const int l = __builtin_amdgcn_readfirstlane(p & (L_ - 1));
  const int c = threadIdx.x & 63;

  float sre = 0.f, sim = 0.f, ssq = 0.f;
  fft_bins(seq, b, l, c, [&](int f, float xr, float xi) {
    sre += xr;
    sim += xi;
    ssq += xr * xr + xi * xi;
  });

  __shared__ float red[3][256];
  const int tid = threadIdx.x;
  red[0][tid] = sre;
  red[1][tid] = sim;
  red[2][tid] = ssq;
  __syncthreads();
  if (tid < 64) {
    const float a0 = red[0][tid] + red[0][tid + 64] + red[0][tid + 128] + red[0][tid + 192];
    const float a1 = red[1][tid] + red[1][tid + 64] + red[1][tid + 128] + red[1][tid + 192];
    const float a2 = red[2][tid] + red[2][tid + 64] + red[2][tid + 128] + red[2][tid + 192];
    const int g = b * C_ + tid;
    unsafeAtomicAdd(&acc[g], a0);
    unsafeAtomicAdd(&acc[1024 + g], a1);
    unsafeAtomicAdd(&acc[2048 + g], a2);
  }
}

__global__ void fe_finalize_kernel(float* __restrict__ ws) {
  const int g = blockIdx.x * 256 + threadIdx.x;
  if (g < B_ * C_) {
    const float invN = 1.0f / (float)NLF;
    const float mr = ws[g] * invN;
    const float mi = ws[1024 + g] * invN;
    const float ms = ws[2048 + g] * invN - (mr * mr + mi * mi);
    ws[3072 + g] = mr;
    ws[4096 + g] = mi;
    ws[5120 + g] = rsqrtf(ms);
  }
}

__global__ void __launch_bounds__(256, 2)
fe_write_kernel(const float* __restrict__ seq, const float* __restrict__ ws,
                float* __restrict__ out) {
  const int p = blockIdx.x * 4 + (threadIdx.x >> 6);
  const int b = __builtin_amdgcn_readfirstlane(p >> 9);
  const int l = __builtin_amdgcn_readfirstlane(p & (L_ - 1));
  const int c = threadIdx.x & 63;

  const int g = b * C_ + c;
  const float mr = ws[3072 + g];
  const float mi = ws[4096 + g];
  const float is = ws[5120 + g];

  float* obase = out + (((size_t)(b * L_ + l)) * F_) * C_ + c;

  fft_bins(seq, b, l, c, [&](int f, float xr, float xi) {
    const float dr = xr - mr;
    const float di = xi - mi;
    obase[(size_t)f * C_] = sqrtf(dr * dr + di * di) * is;
  });
}

extern "C" void kernel_launch(void* const* d_in, const int* in_sizes, int n_in,
                              void* d_out, int out_size, void* d_ws, size_t ws_size,
                              hipStream_t stream) {
  const float* seq = (const float*)d_in[0];
  float* out = (float*)d_out;
  float* ws = (float*)d_ws;

  // zero the 3 accumulator arrays (3072 floats)
  hipMemsetAsync(ws, 0, 3072 * sizeof(float), stream);

  const int nblocks = (B_ * L_) / 4;  // 2048 blocks, 4 (b,l) pairs each
  fe_reduce_kernel<<<nblocks, 256, 0, stream>>>(seq, ws);
  fe_finalize_kernel<<<4, 256, 0, stream>>>(ws);
  fe_write_kernel<<<nblocks, 256, 0, stream>>>(seq, ws, out);
}

// Round 2
// 69.762 us; speedup vs baseline: 1.1877x; 1.1877x over previous
//
#include <hip/hip_runtime.h>
#include <math.h>

// FreqEmbedding: seq [16,512,64] f32 -> out [16,512,65,64] f32
// reflect-pad(64) -> hanning(128) frames -> rfft(128) -> complex standardize
// over (L,F) per (B,C) -> abs.
//
// Pass A (reduce): NO FFT. Uses Parseval + symmetry identities:
//   sum_f Re X_f = (X0 + X64)/2            (since w[0] == 0)
//   sum_f Im X_f = -sum_n (w_n G_n) p_n,   G_n = sum_{k=0..64} sin(pi k n/64)
//   sum_f |X_f|^2 = (128 sum w^2 p^2 + X0^2 + X64^2)/2
// -> 4 dot products per (b,l,c) instead of a 64-pt FFT.
// Pass B (write): FFT once, standardize with mu/sigma read from acc, store.

#define B_ 16
#define L_ 512
#define C_ 64
#define W_ 128
#define F_ 65
#define NLF (L_ * F_)  // 33280

// ---------- compile-time trig tables (fold to VALU literals) ----------
constexpr double kPI = 3.14159265358979323846;

constexpr double csin_(double x) {
  while (x > kPI) x -= 2.0 * kPI;
  while (x < -kPI) x += 2.0 * kPI;
  double t = x, s = x, x2 = x * x;
  for (int i = 1; i <= 24; ++i) {
    t *= -x2 / ((2.0 * i) * (2.0 * i + 1.0));
    s += t;
  }
  return s;
}
constexpr double ccos_(double x) { return csin_(kPI / 2.0 - x); }

constexpr int bitrev6(int n) {
  int r = 0;
  for (int i = 0; i < 6; ++i) r |= ((n >> i) & 1) << (5 - i);
  return r;
}

struct Tables {
  float win[128];         // hanning w_n
  float walt[128];        // (-1)^n w_n
  float w2[128];          // w_n^2
  float wg[128];          // w_n * G_n
  float twr[32], twi[32]; // exp(-2*pi*i*j/64)
  float cur[32], cui[32]; // exp(-2*pi*i*k/128), k=0..31
  constexpr Tables() : win(), walt(), w2(), wg(), twr(), twi(), cur(), cui() {
    for (int n = 0; n < 128; ++n) {
      const double wd = 0.5 - 0.5 * ccos_(2.0 * kPI * n / 127.0);
      win[n] = (float)wd;
      walt[n] = (n & 1) ? (float)(-wd) : (float)wd;
      w2[n] = (float)(wd * wd);
      if (n == 0) {
        wg[n] = 0.0f;
      } else {
        // G_n = sin(pi n/2) * sin(65 pi n/128) / sin(pi n/128)
        const double G = csin_(kPI * n / 2.0) * csin_(65.0 * kPI * n / 128.0) /
                         csin_(kPI * n / 128.0);
        wg[n] = (float)(wd * G);
      }
    }
    for (int j = 0; j < 32; ++j) {
      twr[j] = (float)ccos_(2.0 * kPI * j / 64.0);
      twi[j] = (float)(-csin_(2.0 * kPI * j / 64.0));
    }
    for (int k = 0; k < 32; ++k) {
      cur[k] = (float)ccos_(2.0 * kPI * k / 128.0);
      cui[k] = (float)(-csin_(2.0 * kPI * k / 128.0));
    }
  }
};
constexpr Tables TBL{};

// reflect index into [0, 512)
__device__ __forceinline__ int refl(int t) {
  t = t < 0 ? -t : t;
  return t >= L_ ? (2 * (L_ - 1) - t) : t;
}

// Computes 2*rfft(win * frame) bins and feeds them to `consume(f, re, im)`.
// The uniform factor 2 is compensated in the standardization constants.
template <typename F>
__device__ __forceinline__ void fft_bins(const float* __restrict__ seq,
                                         int b, int l, int c, F&& consume) {
  float zr[64], zi[64];
  const float* base = seq + ((size_t)b * L_) * C_ + c;

  // load in bit-reversed order, pack even/odd, apply window
#pragma unroll
  for (int n = 0; n < 64; ++n) {
    const int m = bitrev6(n);
    const int w0 = 2 * m, w1 = 2 * m + 1;
    const int t0 = refl(l + w0 - 64);
    const int t1 = refl(l + w1 - 64);
    zr[n] = base[(size_t)t0 * C_] * TBL.win[w0];
    zi[n] = base[(size_t)t1 * C_] * TBL.win[w1];
  }

  // 64-point complex DIT FFT, fully unrolled, twiddles are literals
#pragma unroll
  for (int s = 0; s < 6; ++s) {
    const int half = 1 << s;
    const int len = half << 1;
#pragma unroll
    for (int j = 0; j < half; ++j) {
      const float wr = TBL.twr[j << (5 - s)];
      const float wi = TBL.twi[j << (5 - s)];
#pragma unroll
      for (int base2 = 0; base2 < 64; base2 += len) {
        const int a = base2 + j;
        const int b2 = a + half;
        const float tr = wr * zr[b2] - wi * zi[b2];
        const float ti = wr * zi[b2] + wi * zr[b2];
        zr[b2] = zr[a] - tr;
        zi[b2] = zi[a] - ti;
        zr[a] += tr;
        zi[a] += ti;
      }
    }
  }

  // unpack real-FFT bins (scaled by 2)
  consume(0, 2.0f * (zr[0] + zi[0]), 0.0f);
  consume(64, 2.0f * (zr[0] - zi[0]), 0.0f);
  consume(32, 2.0f * zr[32], -2.0f * zi[32]);
#pragma unroll
  for (int k = 1; k < 32; ++k) {
    const float cr = TBL.cur[k], ci = TBL.cui[k];
    const float Er = zr[k] + zr[64 - k];
    const float Ei = zi[k] - zi[64 - k];
    const float Or = zi[k] + zi[64 - k];
    const float Oi = zr[64 - k] - zr[k];
    const float wOr = cr * Or - ci * Oi;
    const float wOi = cr * Oi + ci * Or;
    consume(k, Er + wOr, Ei + wOi);
    consume(64 - k, Er - wOr, wOi - Ei);
  }
}

// ws layout (floats): [0..1023] sum_re, [1024..2047] sum_im, [2048..3071] sum_sq
// (all at TRUE rfft scale; write kernel compensates its 2x bins)
__global__ void __launch_bounds__(256)
fe_reduce_kernel(const float* __restrict__ seq, float* __restrict__ acc) {
  const int p = blockIdx.x * 4 + (threadIdx.x >> 6);
  const int b = __builtin_amdgcn_readfirstlane(p >> 9);
  const int l = __builtin_amdgcn_readfirstlane(p & (L_ - 1));
  const int c = threadIdx.x & 63;

  const float* base = seq + ((size_t)b * L_) * C_ + c;

  float x0 = 0.f, x64 = 0.f, p2 = 0.f, d2 = 0.f;
#pragma unroll
  for (int n = 0; n < 128; ++n) {
    const int t = refl(l + n - 64);
    const float v = base[(size_t)t * C_];
    x0 += TBL.win[n] * v;
    x64 += TBL.walt[n] * v;
    const float wv = TBL.w2[n] * v;
    p2 += wv * v;
    d2 += TBL.wg[n] * v;
  }

  const float sre = 0.5f * (x0 + x64);
  const float sim = -d2;
  const float ssq = 64.0f * p2 + 0.5f * (x0 * x0 + x64 * x64);

  __shared__ float red[3][256];
  const int tid = threadIdx.x;
  red[0][tid] = sre;
  red[1][tid] = sim;
  red[2][tid] = ssq;
  __syncthreads();
  if (tid < 64) {
    const float a0 = red[0][tid] + red[0][tid + 64] + red[0][tid + 128] + red[0][tid + 192];
    const float a1 = red[1][tid] + red[1][tid + 64] + red[1][tid + 128] + red[1][tid + 192];
    const float a2 = red[2][tid] + red[2][tid + 64] + red[2][tid + 128] + red[2][tid + 192];
    const int g = b * C_ + tid;
    unsafeAtomicAdd(&acc[g], a0);
    unsafeAtomicAdd(&acc[1024 + g], a1);
    unsafeAtomicAdd(&acc[2048 + g], a2);
  }
}

__global__ void __launch_bounds__(256, 2)
fe_write_kernel(const float* __restrict__ seq, const float* __restrict__ acc,
                float* __restrict__ out) {
  const int p = blockIdx.x * 4 + (threadIdx.x >> 6);
  const int b = __builtin_amdgcn_readfirstlane(p >> 9);
  const int l = __builtin_amdgcn_readfirstlane(p & (L_ - 1));
  const int c = threadIdx.x & 63;

  // fused finalize: true-scale sums -> constants matching the 2x bins
  const int g = b * C_ + c;
  const float invN = 1.0f / (float)NLF;
  const float sr = acc[g] * invN;
  const float si = acc[1024 + g] * invN;
  const float qq = acc[2048 + g] * invN;
  const float var = qq - sr * sr - si * si;
  const float mr = 2.0f * sr;
  const float mi = 2.0f * si;
  const float is = 0.5f * rsqrtf(var);

  float* obase = out + (((size_t)(b * L_ + l)) * F_) * C_ + c;

  fft_bins(seq, b, l, c, [&](int f, float xr, float xi) {
    const float dr = xr - mr;
    const float di = xi - mi;
    obase[(size_t)f * C_] = sqrtf(dr * dr + di * di) * is;
  });
}

extern "C" void kernel_launch(void* const* d_in, const int* in_sizes, int n_in,
                              void* d_out, int out_size, void* d_ws, size_t ws_size,
                              hipStream_t stream) {
  const float* seq = (const float*)d_in[0];
  float* out = (float*)d_out;
  float* ws = (float*)d_ws;

  // zero the 3 accumulator arrays (3072 floats)
  hipMemsetAsync(ws, 0, 3072 * sizeof(float), stream);

  const int nblocks = (B_ * L_) / 4;  // 2048 blocks, 4 (b,l) pairs each
  fe_reduce_kernel<<<nblocks, 256, 0, stream>>>(seq, ws);
  fe_write_kernel<<<nblocks, 256, 0, stream>>>(seq, ws, out);
}

// Round 3
// 62.941 us; speedup vs baseline: 1.3164x; 1.1084x over previous
//
#include <hip/hip_runtime.h>
#include <math.h>

// FreqEmbedding: seq [16,512,64] f32 -> out [16,512,65,64] f32
// reflect-pad(64) -> hanning(128) frames -> rfft(128) -> complex standardize
// over (L,F) per (B,C) -> abs.
//
// Pass A (reduce): NO FFT — Parseval + symmetry identities (4 dot products).
// Pass B (write): FFT once, standardize, store NONTEMPORAL (keep input in L2).

#define B_ 16
#define L_ 512
#define C_ 64
#define W_ 128
#define F_ 65
#define NLF (L_ * F_)  // 33280

// ---------- compile-time trig tables (fold to VALU literals) ----------
constexpr double kPI = 3.14159265358979323846;

constexpr double csin_(double x) {
  while (x > kPI) x -= 2.0 * kPI;
  while (x < -kPI) x += 2.0 * kPI;
  double t = x, s = x, x2 = x * x;
  for (int i = 1; i <= 24; ++i) {
    t *= -x2 / ((2.0 * i) * (2.0 * i + 1.0));
    s += t;
  }
  return s;
}
constexpr double ccos_(double x) { return csin_(kPI / 2.0 - x); }

constexpr int bitrev6(int n) {
  int r = 0;
  for (int i = 0; i < 6; ++i) r |= ((n >> i) & 1) << (5 - i);
  return r;
}

struct Tables {
  float win[128];         // hanning w_n
  float walt[128];        // (-1)^n w_n
  float w2[128];          // w_n^2
  float wg[128];          // w_n * G_n
  float twr[32], twi[32]; // exp(-2*pi*i*j/64)
  float cur[32], cui[32]; // exp(-2*pi*i*k/128), k=0..31
  constexpr Tables() : win(), walt(), w2(), wg(), twr(), twi(), cur(), cui() {
    for (int n = 0; n < 128; ++n) {
      const double wd = 0.5 - 0.5 * ccos_(2.0 * kPI * n / 127.0);
      win[n] = (float)wd;
      walt[n] = (n & 1) ? (float)(-wd) : (float)wd;
      w2[n] = (float)(wd * wd);
      if (n == 0) {
        wg[n] = 0.0f;
      } else {
        // G_n = sin(pi n/2) * sin(65 pi n/128) / sin(pi n/128)
        const double G = csin_(kPI * n / 2.0) * csin_(65.0 * kPI * n / 128.0) /
                         csin_(kPI * n / 128.0);
        wg[n] = (float)(wd * G);
      }
    }
    for (int j = 0; j < 32; ++j) {
      twr[j] = (float)ccos_(2.0 * kPI * j / 64.0);
      twi[j] = (float)(-csin_(2.0 * kPI * j / 64.0));
    }
    for (int k = 0; k < 32; ++k) {
      cur[k] = (float)ccos_(2.0 * kPI * k / 128.0);
      cui[k] = (float)(-csin_(2.0 * kPI * k / 128.0));
    }
  }
};
constexpr Tables TBL{};

// reflect index into [0, 512)
__device__ __forceinline__ int refl(int t) {
  t = t < 0 ? -t : t;
  return t >= L_ ? (2 * (L_ - 1) - t) : t;
}

__device__ __forceinline__ float fast_sqrt(float x) {
  float r;
  asm("v_sqrt_f32 %0, %1" : "=v"(r) : "v"(x));
  return r;
}

// Computes 2*rfft(win * frame) bins and feeds them to `consume(f, re, im)`.
// The uniform factor 2 is compensated in the standardization constants.
template <typename F>
__device__ __forceinline__ void fft_bins(const float* __restrict__ seq,
                                         int b, int l, int c, F&& consume) {
  float zr[64], zi[64];
  const float* base = seq + ((size_t)b * L_) * C_ + c;

  // load in bit-reversed order, pack even/odd, apply window
#pragma unroll
  for (int n = 0; n < 64; ++n) {
    const int m = bitrev6(n);
    const int w0 = 2 * m, w1 = 2 * m + 1;
    const int t0 = refl(l + w0 - 64);
    const int t1 = refl(l + w1 - 64);
    zr[n] = base[(size_t)t0 * C_] * TBL.win[w0];
    zi[n] = base[(size_t)t1 * C_] * TBL.win[w1];
  }

  // 64-point complex DIT FFT, fully unrolled, twiddles are literals
#pragma unroll
  for (int s = 0; s < 6; ++s) {
    const int half = 1 << s;
    const int len = half << 1;
#pragma unroll
    for (int j = 0; j < half; ++j) {
      const float wr = TBL.twr[j << (5 - s)];
      const float wi = TBL.twi[j << (5 - s)];
#pragma unroll
      for (int base2 = 0; base2 < 64; base2 += len) {
        const int a = base2 + j;
        const int b2 = a + half;
        const float tr = wr * zr[b2] - wi * zi[b2];
        const float ti = wr * zi[b2] + wi * zr[b2];
        zr[b2] = zr[a] - tr;
        zi[b2] = zi[a] - ti;
        zr[a] += tr;
        zi[a] += ti;
      }
    }
  }

  // unpack real-FFT bins (scaled by 2)
  consume(0, 2.0f * (zr[0] + zi[0]), 0.0f);
  consume(64, 2.0f * (zr[0] - zi[0]), 0.0f);
  consume(32, 2.0f * zr[32], -2.0f * zi[32]);
#pragma unroll
  for (int k = 1; k < 32; ++k) {
    const float cr = TBL.cur[k], ci = TBL.cui[k];
    const float Er = zr[k] + zr[64 - k];
    const float Ei = zi[k] - zi[64 - k];
    const float Or = zi[k] + zi[64 - k];
    const float Oi = zr[64 - k] - zr[k];
    const float wOr = cr * Or - ci * Oi;
    const float wOi = cr * Oi + ci * Or;
    consume(k, Er + wOr, Ei + wOi);
    consume(64 - k, Er - wOr, wOi - Ei);
  }
}

// ws layout (floats): [0..1023] sum_re, [1024..2047] sum_im, [2048..3071] sum_sq
// (all at TRUE rfft scale; write kernel compensates its 2x bins)
__global__ void __launch_bounds__(256)
fe_reduce_kernel(const float* __restrict__ seq, float* __restrict__ acc) {
  const int p = blockIdx.x * 4 + (threadIdx.x >> 6);
  const int b = __builtin_amdgcn_readfirstlane(p >> 9);
  const int l = __builtin_amdgcn_readfirstlane(p & (L_ - 1));
  const int c = threadIdx.x & 63;

  const float* base = seq + ((size_t)b * L_) * C_ + c;

  float x0 = 0.f, x64 = 0.f, p2 = 0.f, d2 = 0.f;
#pragma unroll
  for (int n = 0; n < 128; ++n) {
    const int t = refl(l + n - 64);
    const float v = base[(size_t)t * C_];
    x0 += TBL.win[n] * v;
    x64 += TBL.walt[n] * v;
    const float wv = TBL.w2[n] * v;
    p2 += wv * v;
    d2 += TBL.wg[n] * v;
  }

  const float sre = 0.5f * (x0 + x64);
  const float sim = -d2;
  const float ssq = 64.0f * p2 + 0.5f * (x0 * x0 + x64 * x64);

  __shared__ float red[3][256];
  const int tid = threadIdx.x;
  red[0][tid] = sre;
  red[1][tid] = sim;
  red[2][tid] = ssq;
  __syncthreads();
  if (tid < 64) {
    const float a0 = red[0][tid] + red[0][tid + 64] + red[0][tid + 128] + red[0][tid + 192];
    const float a1 = red[1][tid] + red[1][tid + 64] + red[1][tid + 128] + red[1][tid + 192];
    const float a2 = red[2][tid] + red[2][tid + 64] + red[2][tid + 128] + red[2][tid + 192];
    const int g = b * C_ + tid;
    unsafeAtomicAdd(&acc[g], a0);
    unsafeAtomicAdd(&acc[1024 + g], a1);
    unsafeAtomicAdd(&acc[2048 + g], a2);
  }
}

__global__ void __launch_bounds__(256, 2)
fe_write_kernel(const float* __restrict__ seq, const float* __restrict__ acc,
                float* __restrict__ out) {
  const int p = blockIdx.x * 4 + (threadIdx.x >> 6);
  const int b = __builtin_amdgcn_readfirstlane(p >> 9);
  const int l = __builtin_amdgcn_readfirstlane(p & (L_ - 1));
  const int c = threadIdx.x & 63;

  // fused finalize: true-scale sums -> constants matching the 2x bins
  const int g = b * C_ + c;
  const float invN = 1.0f / (float)NLF;
  const float sr = acc[g] * invN;
  const float si = acc[1024 + g] * invN;
  const float qq = acc[2048 + g] * invN;
  const float var = qq - sr * sr - si * si;
  const float mr = 2.0f * sr;
  const float mi = 2.0f * si;
  const float is = 0.5f * rsqrtf(var);

  float* obase = out + (((size_t)(b * L_ + l)) * F_) * C_ + c;

  fft_bins(seq, b, l, c, [&](int f, float xr, float xi) {
    const float dr = xr - mr;
    const float di = xi - mi;
    const float amp = fast_sqrt(__builtin_fmaf(dr, dr, di * di)) * is;
    __builtin_nontemporal_store(amp, &obase[(size_t)f * C_]);
  });
}

extern "C" void kernel_launch(void* const* d_in, const int* in_sizes, int n_in,
                              void* d_out, int out_size, void* d_ws, size_t ws_size,
                              hipStream_t stream) {
  const float* seq = (const float*)d_in[0];
  float* out = (float*)d_out;
  float* ws = (float*)d_ws;

  // zero the 3 accumulator arrays (3072 floats)
  hipMemsetAsync(ws, 0, 3072 * sizeof(float), stream);

  const int nblocks = (B_ * L_) / 4;  // 2048 blocks, 4 (b,l) pairs each
  fe_reduce_kernel<<<nblocks, 256, 0, stream>>>(seq, ws);
  fe_write_kernel<<<nblocks, 256, 0, stream>>>(seq, ws, out);
}

// Round 4
// 62.323 us; speedup vs baseline: 1.3295x; 1.0099x over previous
//
#include <hip/hip_runtime.h>
#include <math.h>

// FreqEmbedding: seq [16,512,64] f32 -> out [16,512,65,64] f32
// reflect-pad(64) -> hanning(128) frames -> rfft(128) -> complex standardize
// over (L,F) per (B,C) -> abs.
//
// Pass A (reduce): NO FFT — Parseval + symmetry identities (4 dot products).
// Pass B (write): FFT once, standardize, store NONTEMPORAL (keep input in L2).
//   Round 4: __launch_bounds__(256,3) — cap VGPR ~168 for 3 waves/SIMD
//   (was 2). FFT state floor = 128 VGPR; expect fit without scratch.

#define B_ 16
#define L_ 512
#define C_ 64
#define W_ 128
#define F_ 65
#define NLF (L_ * F_)  // 33280

// ---------- compile-time trig tables (fold to VALU literals) ----------
constexpr double kPI = 3.14159265358979323846;

constexpr double csin_(double x) {
  while (x > kPI) x -= 2.0 * kPI;
  while (x < -kPI) x += 2.0 * kPI;
  double t = x, s = x, x2 = x * x;
  for (int i = 1; i <= 24; ++i) {
    t *= -x2 / ((2.0 * i) * (2.0 * i + 1.0));
    s += t;
  }
  return s;
}
constexpr double ccos_(double x) { return csin_(kPI / 2.0 - x); }

constexpr int bitrev6(int n) {
  int r = 0;
  for (int i = 0; i < 6; ++i) r |= ((n >> i) & 1) << (5 - i);
  return r;
}

struct Tables {
  float win[128];         // hanning w_n
  float walt[128];        // (-1)^n w_n
  float w2[128];          // w_n^2
  float wg[128];          // w_n * G_n
  float twr[32], twi[32]; // exp(-2*pi*i*j/64)
  float cur[32], cui[32]; // exp(-2*pi*i*k/128), k=0..31
  constexpr Tables() : win(), walt(), w2(), wg(), twr(), twi(), cur(), cui() {
    for (int n = 0; n < 128; ++n) {
      const double wd = 0.5 - 0.5 * ccos_(2.0 * kPI * n / 127.0);
      win[n] = (float)wd;
      walt[n] = (n & 1) ? (float)(-wd) : (float)wd;
      w2[n] = (float)(wd * wd);
      if (n == 0) {
        wg[n] = 0.0f;
      } else {
        // G_n = sin(pi n/2) * sin(65 pi n/128) / sin(pi n/128)
        const double G = csin_(kPI * n / 2.0) * csin_(65.0 * kPI * n / 128.0) /
                         csin_(kPI * n / 128.0);
        wg[n] = (float)(wd * G);
      }
    }
    for (int j = 0; j < 32; ++j) {
      twr[j] = (float)ccos_(2.0 * kPI * j / 64.0);
      twi[j] = (float)(-csin_(2.0 * kPI * j / 64.0));
    }
    for (int k = 0; k < 32; ++k) {
      cur[k] = (float)ccos_(2.0 * kPI * k / 128.0);
      cui[k] = (float)(-csin_(2.0 * kPI * k / 128.0));
    }
  }
};
constexpr Tables TBL{};

// reflect index into [0, 512)
__device__ __forceinline__ int refl(int t) {
  t = t < 0 ? -t : t;
  return t >= L_ ? (2 * (L_ - 1) - t) : t;
}

__device__ __forceinline__ float fast_sqrt(float x) {
  float r;
  asm("v_sqrt_f32 %0, %1" : "=v"(r) : "v"(x));
  return r;
}

// Computes 2*rfft(win * frame) bins and feeds them to `consume(f, re, im)`.
// The uniform factor 2 is compensated in the standardization constants.
template <typename F>
__device__ __forceinline__ void fft_bins(const float* __restrict__ seq,
                                         int b, int l, int c, F&& consume) {
  float zr[64], zi[64];
  const float* base = seq + ((size_t)b * L_) * C_ + c;

  // load in bit-reversed order, pack even/odd, apply window
#pragma unroll
  for (int n = 0; n < 64; ++n) {
    const int m = bitrev6(n);
    const int w0 = 2 * m, w1 = 2 * m + 1;
    const int t0 = refl(l + w0 - 64);
    const int t1 = refl(l + w1 - 64);
    zr[n] = base[(size_t)t0 * C_] * TBL.win[w0];
    zi[n] = base[(size_t)t1 * C_] * TBL.win[w1];
  }

  // 64-point complex DIT FFT, fully unrolled, twiddles are literals
#pragma unroll
  for (int s = 0; s < 6; ++s) {
    const int half = 1 << s;
    const int len = half << 1;
#pragma unroll
    for (int j = 0; j < half; ++j) {
      const float wr = TBL.twr[j << (5 - s)];
      const float wi = TBL.twi[j << (5 - s)];
#pragma unroll
      for (int base2 = 0; base2 < 64; base2 += len) {
        const int a = base2 + j;
        const int b2 = a + half;
        const float tr = wr * zr[b2] - wi * zi[b2];
        const float ti = wr * zi[b2] + wi * zr[b2];
        zr[b2] = zr[a] - tr;
        zi[b2] = zi[a] - ti;
        zr[a] += tr;
        zi[a] += ti;
      }
    }
  }

  // unpack real-FFT bins (scaled by 2)
  consume(0, 2.0f * (zr[0] + zi[0]), 0.0f);
  consume(64, 2.0f * (zr[0] - zi[0]), 0.0f);
  consume(32, 2.0f * zr[32], -2.0f * zi[32]);
#pragma unroll
  for (int k = 1; k < 32; ++k) {
    const float cr = TBL.cur[k], ci = TBL.cui[k];
    const float Er = zr[k] + zr[64 - k];
    const float Ei = zi[k] - zi[64 - k];
    const float Or = zi[k] + zi[64 - k];
    const float Oi = zr[64 - k] - zr[k];
    const float wOr = cr * Or - ci * Oi;
    const float wOi = cr * Oi + ci * Or;
    consume(k, Er + wOr, Ei + wOi);
    consume(64 - k, Er - wOr, wOi - Ei);
  }
}

// ws layout (floats): [0..1023] sum_re, [1024..2047] sum_im, [2048..3071] sum_sq
// (all at TRUE rfft scale; write kernel compensates its 2x bins)
__global__ void __launch_bounds__(256)
fe_reduce_kernel(const float* __restrict__ seq, float* __restrict__ acc) {
  const int p = blockIdx.x * 4 + (threadIdx.x >> 6);
  const int b = __builtin_amdgcn_readfirstlane(p >> 9);
  const int l = __builtin_amdgcn_readfirstlane(p & (L_ - 1));
  const int c = threadIdx.x & 63;

  const float* base = seq + ((size_t)b * L_) * C_ + c;

  float x0 = 0.f, x64 = 0.f, p2 = 0.f, d2 = 0.f;
#pragma unroll
  for (int n = 0; n < 128; ++n) {
    const int t = refl(l + n - 64);
    const float v = base[(size_t)t * C_];
    x0 += TBL.win[n] * v;
    x64 += TBL.walt[n] * v;
    const float wv = TBL.w2[n] * v;
    p2 += wv * v;
    d2 += TBL.wg[n] * v;
  }

  const float sre = 0.5f * (x0 + x64);
  const float sim = -d2;
  const float ssq = 64.0f * p2 + 0.5f * (x0 * x0 + x64 * x64);

  __shared__ float red[3][256];
  const int tid = threadIdx.x;
  red[0][tid] = sre;
  red[1][tid] = sim;
  red[2][tid] = ssq;
  __syncthreads();
  if (tid < 64) {
    const float a0 = red[0][tid] + red[0][tid + 64] + red[0][tid + 128] + red[0][tid + 192];
    const float a1 = red[1][tid] + red[1][tid + 64] + red[1][tid + 128] + red[1][tid + 192];
    const float a2 = red[2][tid] + red[2][tid + 64] + red[2][tid + 128] + red[2][tid + 192];
    const int g = b * C_ + tid;
    unsafeAtomicAdd(&acc[g], a0);
    unsafeAtomicAdd(&acc[1024 + g], a1);
    unsafeAtomicAdd(&acc[2048 + g], a2);
  }
}

__global__ void __launch_bounds__(256, 3)
fe_write_kernel(const float* __restrict__ seq, const float* __restrict__ acc,
                float* __restrict__ out) {
  const int p = blockIdx.x * 4 + (threadIdx.x >> 6);
  const int b = __builtin_amdgcn_readfirstlane(p >> 9);
  const int l = __builtin_amdgcn_readfirstlane(p & (L_ - 1));
  const int c = threadIdx.x & 63;

  // fused finalize: true-scale sums -> constants matching the 2x bins
  const int g = b * C_ + c;
  const float invN = 1.0f / (float)NLF;
  const float sr = acc[g] * invN;
  const float si = acc[1024 + g] * invN;
  const float qq = acc[2048 + g] * invN;
  const float var = qq - sr * sr - si * si;
  const float mr = 2.0f * sr;
  const float mi = 2.0f * si;
  const float is = 0.5f * rsqrtf(var);

  float* obase = out + (((size_t)(b * L_ + l)) * F_) * C_ + c;

  fft_bins(seq, b, l, c, [&](int f, float xr, float xi) {
    const float dr = xr - mr;
    const float di = xi - mi;
    const float amp = fast_sqrt(__builtin_fmaf(dr, dr, di * di)) * is;
    __builtin_nontemporal_store(amp, &obase[(size_t)f * C_]);
  });
}

extern "C" void kernel_launch(void* const* d_in, const int* in_sizes, int n_in,
                              void* d_out, int out_size, void* d_ws, size_t ws_size,
                              hipStream_t stream) {
  const float* seq = (const float*)d_in[0];
  float* out = (float*)d_out;
  float* ws = (float*)d_ws;

  // zero the 3 accumulator arrays (3072 floats)
  hipMemsetAsync(ws, 0, 3072 * sizeof(float), stream);

  const int nblocks = (B_ * L_) / 4;  // 2048 blocks, 4 (b,l) pairs each
  fe_reduce_kernel<<<nblocks, 256, 0, stream>>>(seq, ws);
  fe_write_kernel<<<nblocks, 256, 0, stream>>>(seq, ws, out);
}